// Round 4
// baseline (7310.918 us; speedup 1.0000x reference)
//
#include <hip/hip_runtime.h>

// GMAN-ish pipeline, fully fused. support = I so every (b,n) token is independent.
// B=64, P=Q=12, N=1024, D=64. Output [B,Q,N] fp32.
//
// R4: j-split across waves (R3 still spilled 1 GB: token-per-lane with D=64 means
// >=128 live floats/lane no matter how phases are cut).
//  - block = 256 thr = 4 waves, 64 tokens/block (lane = token, shared by all waves).
//  - wave w owns output quarter: r-cols [16w,16w+16), u-cols [64+16w,..), c-cols [16w,..).
//  - per-lane regs: ga[32] + cc[16] + 8-wide ds_read chunks  ~= 80 VGPRs -> no spills.
//  - xe/s1/s2/rs in LDS [64 k][64 t] (lanes stride-1, 2 lanes/bank = conflict-free).
//  - candidate x-part folded into gates k-loop -> xe dead after gates -> rs ALIASES xe:
//    LDS = 48 KB -> 3 blocks/CU -> 3 waves/SIMD.
//  - weights pre-transposed per quarter: Wgq[q][k][64] (32 gate cols x{x,s}),
//    Wcxq/Wcsq[q][k][16] -> contiguous s_load_dwordx16 streams, 1 SGPR operand per FMA.

#define NB 1024

__device__ __forceinline__ float fexp(float x) {
    return __builtin_amdgcn_exp2f(x * 1.44269504088896341f);
}
__device__ __forceinline__ float fsigmoid(float x) {
    return __builtin_amdgcn_rcpf(1.0f + fexp(-x));   // exp overflow -> inf -> rcp -> 0 : OK
}
__device__ __forceinline__ float ftanh(float x) {
    return 1.0f - 2.0f * __builtin_amdgcn_rcpf(1.0f + fexp(2.0f * x));  // saturates to +-1
}

// ---------------- weight re-layout ----------------
// ws float offsets:
//   0      L1 Wgq  [4][64][64]   (c<32: gate col weights vs x ; c>=32: same cols vs s)
//   16384  L1 Wcxq [4][64][16]
//   20480  L1 Wcsq [4][64][16]
//   24576  L2 Wgq / 40960 L2 Wcxq / 45056 L2 Wcsq
//   49152  Win2q [4][64][16]
//   53248  Wo1q  [4][64][16]
//   57344  seT   [64][1024]  (b_in2 folded)
//   122880 teo   [64*24? no: B*P][64] = [768][64]
__global__ void prep_all(const float* __restrict__ Wg1, const float* __restrict__ Wc1,
                         const float* __restrict__ Wg2, const float* __restrict__ Wc2,
                         const float* __restrict__ Win2, const float* __restrict__ Wo1,
                         float* __restrict__ ws) {
    int i = blockIdx.x * 256 + threadIdx.x;
    if (i >= 57344) return;
    if (i < 24576) {            // layer 1
        const float* Wg = Wg1; const float* Wc = Wc1; int o = i;
        float v;
        if (o < 16384) {
            int q = o >> 12, r = o & 4095, k = r >> 6, c = r & 63;
            int cc = c & 31;
            int jj = (cc < 16) ? (q * 16 + cc) : (64 + q * 16 + (cc - 16));
            v = (c < 32) ? Wg[k * 128 + jj] + Wg[(128 + k) * 128 + jj]
                         : Wg[(64 + k) * 128 + jj] + Wg[(192 + k) * 128 + jj];
        } else if (o < 20480) {
            int r = o - 16384; int q = r >> 10; r &= 1023; int k = r >> 4, j = r & 15;
            int col = q * 16 + j;
            v = Wc[k * 64 + col] + Wc[(128 + k) * 64 + col];
        } else {
            int r = o - 20480; int q = r >> 10; r &= 1023; int k = r >> 4, j = r & 15;
            int col = q * 16 + j;
            v = Wc[(64 + k) * 64 + col] + Wc[(192 + k) * 64 + col];
        }
        ws[i] = v;
    } else if (i < 49152) {     // layer 2
        const float* Wg = Wg2; const float* Wc = Wc2; int o = i - 24576;
        float v;
        if (o < 16384) {
            int q = o >> 12, r = o & 4095, k = r >> 6, c = r & 63;
            int cc = c & 31;
            int jj = (cc < 16) ? (q * 16 + cc) : (64 + q * 16 + (cc - 16));
            v = (c < 32) ? Wg[k * 128 + jj] + Wg[(128 + k) * 128 + jj]
                         : Wg[(64 + k) * 128 + jj] + Wg[(192 + k) * 128 + jj];
        } else if (o < 20480) {
            int r = o - 16384; int q = r >> 10; r &= 1023; int k = r >> 4, j = r & 15;
            int col = q * 16 + j;
            v = Wc[k * 64 + col] + Wc[(128 + k) * 64 + col];
        } else {
            int r = o - 20480; int q = r >> 10; r &= 1023; int k = r >> 4, j = r & 15;
            int col = q * 16 + j;
            v = Wc[(64 + k) * 64 + col] + Wc[(192 + k) * 64 + col];
        }
        ws[i] = v;
    } else if (i < 53248) {     // Win2q[q][j][16] = Win2[j*64 + q*16 + d]
        int o = i - 49152; int q = o >> 10; o &= 1023; int j = o >> 4, d = o & 15;
        ws[i] = Win2[j * 64 + q * 16 + d];
    } else {                    // Wo1q[q][k][16] = Wo1[k*64 + q*16 + j]
        int o = i - 53248; int q = o >> 10; o &= 1023; int k = o >> 4, j = o & 15;
        ws[i] = Wo1[k * 64 + q * 16 + j];
    }
}

// ---- se = relu(SE@W1+b1)@W2+b2, stored TRANSPOSED [d][n] with b_in2 folded in.
__global__ void prep_se(const float* __restrict__ SE, const float* __restrict__ W1,
                        const float* __restrict__ b1, const float* __restrict__ W2,
                        const float* __restrict__ b2, const float* __restrict__ bin2,
                        float* __restrict__ seT) {
    __shared__ float h[64];
    int n = blockIdx.x, d = threadIdx.x;
    float acc = b1[d];
    for (int k = 0; k < 64; k++) acc = fmaf(SE[n * 64 + k], W1[k * 64 + d], acc);
    h[d] = fmaxf(acc, 0.0f);
    __syncthreads();
    float acc2 = b2[d];
    for (int k = 0; k < 64; k++) acc2 = fmaf(h[k], W2[k * 64 + d], acc2);
    seT[d * NB + n] = acc2 + bin2[d];
}

// ---- te[b,p,:] = relu(Wte1[dow]+Wte1[7+tod]+b1)@W2+b2   (one-hot matmul == row gather)
__global__ void prep_te(const int* __restrict__ TE, const float* __restrict__ W1,
                        const float* __restrict__ b1, const float* __restrict__ W2,
                        const float* __restrict__ b2, float* __restrict__ teo) {
    __shared__ float h[64];
    int bp = blockIdx.x;            // b*12 + p
    int b = bp / 12, p = bp - b * 12;
    int d = threadIdx.x;
    int dow = TE[(b * 24 + p) * 2 + 0];
    int tod = TE[(b * 24 + p) * 2 + 1];
    float v = W1[dow * 64 + d] + W1[(7 + tod) * 64 + d] + b1[d];
    h[d] = fmaxf(v, 0.0f);
    __syncthreads();
    float acc = b2[d];
    for (int k = 0; k < 64; k++) acc = fmaf(h[k], W2[k * 64 + d], acc);
    teo[bp * 64 + d] = acc;
}

// one GRU step, j-quarter per wave. XIN may alias RSb (xe dead after gates: B1 guards).
__device__ __forceinline__ void layer_step(
    const float* __restrict__ XIN, float* __restrict__ S, float* __restrict__ RSb,
    const float* __restrict__ Wg, const float* __restrict__ Wcx, const float* __restrict__ Wcs,
    const float* __restrict__ bg, const float* __restrict__ bc, int w, int t) {
    float ga[32], cc[16];
    #pragma unroll
    for (int c = 0; c < 16; c++) ga[c] = bg[w * 16 + c];            // r bias
    #pragma unroll
    for (int c = 0; c < 16; c++) ga[16 + c] = bg[64 + w * 16 + c];  // u bias
    #pragma unroll
    for (int j = 0; j < 16; j++) cc[j] = bc[w * 16 + j];
    #pragma unroll 1
    for (int kc = 0; kc < 8; kc++) {
        float xv[8], sv[8];
        #pragma unroll
        for (int i = 0; i < 8; i++) {
            int k = kc * 8 + i;
            xv[i] = XIN[k * 64 + t];
            sv[i] = S[k * 64 + t];
        }
        #pragma unroll
        for (int i = 0; i < 8; i++) {
            int k = kc * 8 + i;
            const float* wk  = Wg + k * 64;
            const float* wcx = Wcx + k * 16;
            #pragma unroll
            for (int c = 0; c < 32; c++)
                ga[c] = fmaf(xv[i], wk[c], fmaf(sv[i], wk[32 + c], ga[c]));
            #pragma unroll
            for (int j = 0; j < 16; j++) cc[j] = fmaf(xv[i], wcx[j], cc[j]);
        }
    }
    __syncthreads();   // B1: all XIN reads done (RSb may alias XIN)
    #pragma unroll
    for (int j = 0; j < 16; j++)
        RSb[(w * 16 + j) * 64 + t] = fsigmoid(ga[j]) * S[(w * 16 + j) * 64 + t];
    __syncthreads();   // B2: rs visible to all waves
    #pragma unroll 1
    for (int kc = 0; kc < 8; kc++) {
        float rv[8];
        #pragma unroll
        for (int i = 0; i < 8; i++) rv[i] = RSb[(kc * 8 + i) * 64 + t];
        #pragma unroll
        for (int i = 0; i < 8; i++) {
            const float* wk = Wcs + (kc * 8 + i) * 16;
            #pragma unroll
            for (int j = 0; j < 16; j++) cc[j] = fmaf(rv[i], wk[j], cc[j]);
        }
    }
    #pragma unroll
    for (int j = 0; j < 16; j++) {
        const float u = fsigmoid(ga[16 + j]);
        const float sold = S[(w * 16 + j) * 64 + t];
        S[(w * 16 + j) * 64 + t] = u * sold + (1.0f - u) * ftanh(cc[j]);
    }
    __syncthreads();   // B3: state update visible
}

__global__ __launch_bounds__(256, 3) void gman_main(
    const float* __restrict__ X, const float* __restrict__ ws,
    const float* __restrict__ Win1, const float* __restrict__ bin1,
    const float* __restrict__ bg1, const float* __restrict__ bc1,
    const float* __restrict__ bg2, const float* __restrict__ bc2,
    const float* __restrict__ bo1, const float* __restrict__ Wo2,
    const float* __restrict__ bo2, float* __restrict__ out) {
    __shared__ float XEbuf[4096];   // xe[k][t]; aliased as rs[k][t]; aliased as h[j][t]
    __shared__ float S1[4096], S2[4096];

    const int tid = threadIdx.x;
    const int w = tid >> 6;         // wave = j-quarter owner
    const int t = tid & 63;         // lane = token within block
    const int b = blockIdx.x >> 4;
    const int n = ((blockIdx.x & 15) << 6) | t;

    const float* L1Wg  = ws;
    const float* L1Wcx = ws + 16384;
    const float* L1Wcs = ws + 20480;
    const float* L2Wg  = ws + 24576;
    const float* L2Wcx = ws + 40960;
    const float* L2Wcs = ws + 45056;
    const float* Win2q = ws + 49152;
    const float* Wo1q  = ws + 53248;
    const float* seT   = ws + 57344;
    const float* teo   = ws + 122880;

    const float* Wg1w  = L1Wg + w * 4096;
    const float* Wcx1w = L1Wcx + w * 1024;
    const float* Wcs1w = L1Wcs + w * 1024;
    const float* Wg2w  = L2Wg + w * 4096;
    const float* Wcx2w = L2Wcx + w * 1024;
    const float* Wcs2w = L2Wcs + w * 1024;
    const float* Win2w = Win2q + w * 1024;
    const float* Wo1w  = Wo1q + w * 1024;

    // init states (wave w zeroes its 16 rows of each)
    #pragma unroll
    for (int j = 0; j < 16; j++) {
        S1[(w * 16 + j) * 64 + t] = 0.0f;
        S2[(w * 16 + j) * 64 + t] = 0.0f;
    }

    #pragma unroll 1
    for (int p = 0; p < 12; p++) {
        // ---------- xe quarter: se + te + relu(x*Win1+bin1)@Win2 ----------
        const float x = X[(b * 12 + p) * NB + n];
        const float* tep = teo + (b * 12 + p) * 64;     // uniform -> s_load
        float xq[16];
        #pragma unroll
        for (int d = 0; d < 16; d++) xq[d] = seT[(w * 16 + d) * NB + n] + tep[w * 16 + d];
        #pragma unroll 2
        for (int j = 0; j < 64; j++) {
            const float h = fmaxf(fmaf(x, Win1[j], bin1[j]), 0.0f);
            const float* w2 = Win2w + j * 16;
            #pragma unroll
            for (int d = 0; d < 16; d++) xq[d] = fmaf(h, w2[d], xq[d]);
        }
        #pragma unroll
        for (int d = 0; d < 16; d++) XEbuf[(w * 16 + d) * 64 + t] = xq[d];
        __syncthreads();   // B0: xe visible (also covers state init / prev-p rs reads)

        layer_step(XEbuf, S1, XEbuf, Wg1w, Wcx1w, Wcs1w, bg1, bc1, w, t);
        layer_step(S1,    S2, XEbuf, Wg2w, Wcx2w, Wcs2w, bg2, bc2, w, t);
    }

    // ---------- head: h = relu(S2@Wo1+bo1) (into XEbuf), then y quarter ----------
    float hq[16];
    #pragma unroll
    for (int j = 0; j < 16; j++) hq[j] = bo1[w * 16 + j];
    #pragma unroll 1
    for (int kc = 0; kc < 8; kc++) {
        float sv[8];
        #pragma unroll
        for (int i = 0; i < 8; i++) sv[i] = S2[(kc * 8 + i) * 64 + t];
        #pragma unroll
        for (int i = 0; i < 8; i++) {
            const float* wk = Wo1w + (kc * 8 + i) * 16;
            #pragma unroll
            for (int j = 0; j < 16; j++) hq[j] = fmaf(sv[i], wk[j], hq[j]);
        }
    }
    #pragma unroll
    for (int j = 0; j < 16; j++) XEbuf[(w * 16 + j) * 64 + t] = fmaxf(hq[j], 0.0f);
    __syncthreads();
    float y0 = bo2[3 * w], y1 = bo2[3 * w + 1], y2 = bo2[3 * w + 2];
    #pragma unroll 4
    for (int j = 0; j < 64; j++) {
        const float hj = XEbuf[j * 64 + t];
        y0 = fmaf(hj, Wo2[j * 12 + 3 * w + 0], y0);
        y1 = fmaf(hj, Wo2[j * 12 + 3 * w + 1], y1);
        y2 = fmaf(hj, Wo2[j * 12 + 3 * w + 2], y2);
    }
    out[(b * 12 + 3 * w + 0) * NB + n] = y0;
    out[(b * 12 + 3 * w + 1) * NB + n] = y1;
    out[(b * 12 + 3 * w + 2) * NB + n] = y2;
}

extern "C" void kernel_launch(void* const* d_in, const int* in_sizes, int n_in,
                              void* d_out, int out_size, void* d_ws, size_t ws_size,
                              hipStream_t stream) {
    const float* X    = (const float*)d_in[0];
    // d_in[1]=ZC, d_in[2]=ZF unused by the reference
    const float* SE   = (const float*)d_in[3];
    const float* Wse1 = (const float*)d_in[4];
    const float* bse1 = (const float*)d_in[5];
    const float* Wse2 = (const float*)d_in[6];
    const float* bse2 = (const float*)d_in[7];
    const float* Wte1 = (const float*)d_in[8];
    const float* bte1 = (const float*)d_in[9];
    const float* Wte2 = (const float*)d_in[10];
    const float* bte2 = (const float*)d_in[11];
    const float* Win1 = (const float*)d_in[12];
    const float* bin1 = (const float*)d_in[13];
    const float* Win2 = (const float*)d_in[14];
    const float* bin2 = (const float*)d_in[15];
    const float* Wg1  = (const float*)d_in[16];
    const float* bg1  = (const float*)d_in[17];
    const float* Wc1  = (const float*)d_in[18];
    const float* bc1  = (const float*)d_in[19];
    const float* Wg2  = (const float*)d_in[20];
    const float* bg2  = (const float*)d_in[21];
    const float* Wc2  = (const float*)d_in[22];
    const float* bc2  = (const float*)d_in[23];
    const float* Wo1  = (const float*)d_in[24];
    const float* bo1  = (const float*)d_in[25];
    const float* Wo2  = (const float*)d_in[26];
    const float* bo2  = (const float*)d_in[27];
    const int*   TE   = (const int*)d_in[28];

    float* ws  = (float*)d_ws;                 // 172032 floats = 688 KB
    float* seT = ws + 57344;
    float* teo = ws + 122880;
    float* out = (float*)d_out;

    prep_all<<<224, 256, 0, stream>>>(Wg1, Wc1, Wg2, Wc2, Win2, Wo1, ws);
    prep_se<<<1024, 64, 0, stream>>>(SE, Wse1, bse1, Wse2, bse2, bin2, seT);
    prep_te<<<768, 64, 0, stream>>>(TE, Wte1, bte1, Wte2, bte2, teo);
    gman_main<<<1024, 256, 0, stream>>>(X, ws, Win1, bin1, bg1, bc1, bg2, bc2,
                                        bo1, Wo2, bo2, out);
}

// Round 5
// 1504.079 us; speedup vs baseline: 4.8607x; 4.8607x over previous
//
#include <hip/hip_runtime.h>

// GMAN-ish pipeline, fully fused. support = I so every (b,n) token is independent.
// B=64, P=Q=12, N=1024, D=64. Output [B,Q,N] fp32.
//
// R5: R4's j-split was right but w = tid>>6 is DIVERGENT to the compiler's
// uniformity analysis -> all weight loads compiled to per-lane global_load_dword
// (4.1 GB traffic, VALUBusy 9.6%, latency-bound). Fix: readfirstlane(w) makes the
// compiler treat every weight/bias pointer as wave-uniform -> s_load_dwordx16
// streams with SGPR-operand FMAs, zero L1 involvement.
//  - block = 256 thr = 4 waves, 64 tokens/block (lane = token, shared by all waves).
//  - wave w owns output quarter: r-cols [16w,..), u-cols [64+16w,..), c-cols [16w,..).
//  - per-lane regs: ga[32] + cc[16] + chunks ~= 80-110 VGPRs -> no spills.
//  - xe/s1/s2/rs in LDS [64 k][64 t] (lanes stride-1, 2 lanes/bank = conflict-free).
//  - xe dead after gates -> rs ALIASES xe: LDS = 48 KB -> 3 blocks/CU.

#define NB 1024

__device__ __forceinline__ float fexp(float x) {
    return __builtin_amdgcn_exp2f(x * 1.44269504088896341f);
}
__device__ __forceinline__ float fsigmoid(float x) {
    return __builtin_amdgcn_rcpf(1.0f + fexp(-x));   // exp overflow -> inf -> rcp -> 0 : OK
}
__device__ __forceinline__ float ftanh(float x) {
    return 1.0f - 2.0f * __builtin_amdgcn_rcpf(1.0f + fexp(2.0f * x));  // saturates to +-1
}

// ---------------- weight re-layout ----------------
// ws float offsets:
//   0      L1 Wgq  [4][64][64]   (c<32: gate cols vs x ; c>=32: same cols vs s)
//   16384  L1 Wcxq [4][64][16]
//   20480  L1 Wcsq [4][64][16]
//   24576  L2 Wgq / 40960 L2 Wcxq / 45056 L2 Wcsq
//   49152  Win2q [4][64][16]
//   53248  Wo1q  [4][64][16]
//   57344  seT   [64][1024]  (b_in2 folded)
//   122880 teo   [768][64]
__global__ void prep_all(const float* __restrict__ Wg1, const float* __restrict__ Wc1,
                         const float* __restrict__ Wg2, const float* __restrict__ Wc2,
                         const float* __restrict__ Win2, const float* __restrict__ Wo1,
                         float* __restrict__ ws) {
    int i = blockIdx.x * 256 + threadIdx.x;
    if (i >= 57344) return;
    if (i < 24576) {            // layer 1
        const float* Wg = Wg1; const float* Wc = Wc1; int o = i;
        float v;
        if (o < 16384) {
            int q = o >> 12, r = o & 4095, k = r >> 6, c = r & 63;
            int cc = c & 31;
            int jj = (cc < 16) ? (q * 16 + cc) : (64 + q * 16 + (cc - 16));
            v = (c < 32) ? Wg[k * 128 + jj] + Wg[(128 + k) * 128 + jj]
                         : Wg[(64 + k) * 128 + jj] + Wg[(192 + k) * 128 + jj];
        } else if (o < 20480) {
            int r = o - 16384; int q = r >> 10; r &= 1023; int k = r >> 4, j = r & 15;
            int col = q * 16 + j;
            v = Wc[k * 64 + col] + Wc[(128 + k) * 64 + col];
        } else {
            int r = o - 20480; int q = r >> 10; r &= 1023; int k = r >> 4, j = r & 15;
            int col = q * 16 + j;
            v = Wc[(64 + k) * 64 + col] + Wc[(192 + k) * 64 + col];
        }
        ws[i] = v;
    } else if (i < 49152) {     // layer 2
        const float* Wg = Wg2; const float* Wc = Wc2; int o = i - 24576;
        float v;
        if (o < 16384) {
            int q = o >> 12, r = o & 4095, k = r >> 6, c = r & 63;
            int cc = c & 31;
            int jj = (cc < 16) ? (q * 16 + cc) : (64 + q * 16 + (cc - 16));
            v = (c < 32) ? Wg[k * 128 + jj] + Wg[(128 + k) * 128 + jj]
                         : Wg[(64 + k) * 128 + jj] + Wg[(192 + k) * 128 + jj];
        } else if (o < 20480) {
            int r = o - 16384; int q = r >> 10; r &= 1023; int k = r >> 4, j = r & 15;
            int col = q * 16 + j;
            v = Wc[k * 64 + col] + Wc[(128 + k) * 64 + col];
        } else {
            int r = o - 20480; int q = r >> 10; r &= 1023; int k = r >> 4, j = r & 15;
            int col = q * 16 + j;
            v = Wc[(64 + k) * 64 + col] + Wc[(192 + k) * 64 + col];
        }
        ws[i] = v;
    } else if (i < 53248) {     // Win2q[q][j][16] = Win2[j*64 + q*16 + d]
        int o = i - 49152; int q = o >> 10; o &= 1023; int j = o >> 4, d = o & 15;
        ws[i] = Win2[j * 64 + q * 16 + d];
    } else {                    // Wo1q[q][k][16] = Wo1[k*64 + q*16 + j]
        int o = i - 53248; int q = o >> 10; o &= 1023; int k = o >> 4, j = o & 15;
        ws[i] = Wo1[k * 64 + q * 16 + j];
    }
}

// ---- se = relu(SE@W1+b1)@W2+b2, stored TRANSPOSED [d][n] with b_in2 folded in.
__global__ void prep_se(const float* __restrict__ SE, const float* __restrict__ W1,
                        const float* __restrict__ b1, const float* __restrict__ W2,
                        const float* __restrict__ b2, const float* __restrict__ bin2,
                        float* __restrict__ seT) {
    __shared__ float h[64];
    int n = blockIdx.x, d = threadIdx.x;
    float acc = b1[d];
    for (int k = 0; k < 64; k++) acc = fmaf(SE[n * 64 + k], W1[k * 64 + d], acc);
    h[d] = fmaxf(acc, 0.0f);
    __syncthreads();
    float acc2 = b2[d];
    for (int k = 0; k < 64; k++) acc2 = fmaf(h[k], W2[k * 64 + d], acc2);
    seT[d * NB + n] = acc2 + bin2[d];
}

// ---- te[b,p,:] = relu(Wte1[dow]+Wte1[7+tod]+b1)@W2+b2   (one-hot matmul == row gather)
__global__ void prep_te(const int* __restrict__ TE, const float* __restrict__ W1,
                        const float* __restrict__ b1, const float* __restrict__ W2,
                        const float* __restrict__ b2, float* __restrict__ teo) {
    __shared__ float h[64];
    int bp = blockIdx.x;            // b*12 + p
    int b = bp / 12, p = bp - b * 12;
    int d = threadIdx.x;
    int dow = TE[(b * 24 + p) * 2 + 0];
    int tod = TE[(b * 24 + p) * 2 + 1];
    float v = W1[dow * 64 + d] + W1[(7 + tod) * 64 + d] + b1[d];
    h[d] = fmaxf(v, 0.0f);
    __syncthreads();
    float acc = b2[d];
    for (int k = 0; k < 64; k++) acc = fmaf(h[k], W2[k * 64 + d], acc);
    teo[bp * 64 + d] = acc;
}

// one GRU step, j-quarter per wave. XIN may alias RSb (xe dead after gates: B1 guards).
// ALL weight/bias pointers must be derived from readfirstlane'd offsets (s_load path).
__device__ __forceinline__ void layer_step(
    const float* __restrict__ XIN, float* __restrict__ S, float* __restrict__ RSb,
    const float* __restrict__ Wg, const float* __restrict__ Wcx, const float* __restrict__ Wcs,
    const float* __restrict__ bg_r, const float* __restrict__ bg_u,
    const float* __restrict__ bc_w, int w, int t) {
    float ga[32], cc[16];
    #pragma unroll
    for (int c = 0; c < 16; c++) ga[c] = bg_r[c];            // r bias (uniform ptr)
    #pragma unroll
    for (int c = 0; c < 16; c++) ga[16 + c] = bg_u[c];       // u bias (uniform ptr)
    #pragma unroll
    for (int j = 0; j < 16; j++) cc[j] = bc_w[j];
    #pragma unroll 1
    for (int kc = 0; kc < 8; kc++) {
        float xv[8], sv[8];
        #pragma unroll
        for (int i = 0; i < 8; i++) {
            int k = kc * 8 + i;
            xv[i] = XIN[k * 64 + t];
            sv[i] = S[k * 64 + t];
        }
        #pragma unroll
        for (int i = 0; i < 8; i++) {
            int k = kc * 8 + i;
            const float* wk  = Wg + k * 64;     // uniform base -> s_load_dwordx16
            const float* wcx = Wcx + k * 16;
            #pragma unroll
            for (int c = 0; c < 32; c++)
                ga[c] = fmaf(xv[i], wk[c], fmaf(sv[i], wk[32 + c], ga[c]));
            #pragma unroll
            for (int j = 0; j < 16; j++) cc[j] = fmaf(xv[i], wcx[j], cc[j]);
        }
    }
    __syncthreads();   // B1: all XIN reads done (RSb may alias XIN)
    #pragma unroll
    for (int j = 0; j < 16; j++)
        RSb[(w * 16 + j) * 64 + t] = fsigmoid(ga[j]) * S[(w * 16 + j) * 64 + t];
    __syncthreads();   // B2: rs visible to all waves
    #pragma unroll 1
    for (int kc = 0; kc < 8; kc++) {
        float rv[8];
        #pragma unroll
        for (int i = 0; i < 8; i++) rv[i] = RSb[(kc * 8 + i) * 64 + t];
        #pragma unroll
        for (int i = 0; i < 8; i++) {
            const float* wk = Wcs + (kc * 8 + i) * 16;
            #pragma unroll
            for (int j = 0; j < 16; j++) cc[j] = fmaf(rv[i], wk[j], cc[j]);
        }
    }
    #pragma unroll
    for (int j = 0; j < 16; j++) {
        const float u = fsigmoid(ga[16 + j]);
        const float sold = S[(w * 16 + j) * 64 + t];
        S[(w * 16 + j) * 64 + t] = u * sold + (1.0f - u) * ftanh(cc[j]);
    }
    __syncthreads();   // B3: state update visible
}

__global__ __launch_bounds__(256, 3) void gman_main(
    const float* __restrict__ X, const float* __restrict__ ws,
    const float* __restrict__ Win1, const float* __restrict__ bin1,
    const float* __restrict__ bg1, const float* __restrict__ bc1,
    const float* __restrict__ bg2, const float* __restrict__ bc2,
    const float* __restrict__ bo1, const float* __restrict__ Wo2,
    const float* __restrict__ bo2, float* __restrict__ out) {
    __shared__ float XEbuf[4096];   // xe[k][t]; aliased as rs[k][t]; aliased as h[j][t]
    __shared__ float S1[4096], S2[4096];

    const int tid = threadIdx.x;
    const int w = tid >> 6;         // wave id (true wave-uniform)
    const int t = tid & 63;         // lane = token within block
    // Force the compiler to SEE the uniformity -> every derived pointer scalar.
    const int uw = __builtin_amdgcn_readfirstlane(w);
    const int b = blockIdx.x >> 4;
    const int n = ((blockIdx.x & 15) << 6) | t;

    const float* Wg1w  = ws + uw * 4096;
    const float* Wcx1w = ws + 16384 + uw * 1024;
    const float* Wcs1w = ws + 20480 + uw * 1024;
    const float* Wg2w  = ws + 24576 + uw * 4096;
    const float* Wcx2w = ws + 40960 + uw * 1024;
    const float* Wcs2w = ws + 45056 + uw * 1024;
    const float* Win2w = ws + 49152 + uw * 1024;
    const float* Wo1w  = ws + 53248 + uw * 1024;
    const float* seT   = ws + 57344;
    const float* teo   = ws + 122880;

    const float* bg1r = bg1 + uw * 16;  const float* bg1u = bg1 + 64 + uw * 16;
    const float* bc1w = bc1 + uw * 16;
    const float* bg2r = bg2 + uw * 16;  const float* bg2u = bg2 + 64 + uw * 16;
    const float* bc2w = bc2 + uw * 16;

    // init states (wave w zeroes its 16 rows of each)
    #pragma unroll
    for (int j = 0; j < 16; j++) {
        S1[(uw * 16 + j) * 64 + t] = 0.0f;
        S2[(uw * 16 + j) * 64 + t] = 0.0f;
    }

    #pragma unroll 1
    for (int p = 0; p < 12; p++) {
        // ---------- xe quarter: se + te + relu(x*Win1+bin1)@Win2 ----------
        const float x = X[(b * 12 + p) * NB + n];
        const float* tep = teo + (b * 12 + p) * 64 + uw * 16;   // uniform -> s_load
        float xq[16];
        #pragma unroll
        for (int d = 0; d < 16; d++) xq[d] = seT[(uw * 16 + d) * NB + n] + tep[d];
        #pragma unroll 2
        for (int j = 0; j < 64; j++) {
            const float h = fmaxf(fmaf(x, Win1[j], bin1[j]), 0.0f);
            const float* w2 = Win2w + j * 16;
            #pragma unroll
            for (int d = 0; d < 16; d++) xq[d] = fmaf(h, w2[d], xq[d]);
        }
        #pragma unroll
        for (int d = 0; d < 16; d++) XEbuf[(uw * 16 + d) * 64 + t] = xq[d];
        __syncthreads();   // B0: xe visible (also covers state init / prev-p rs reads)

        layer_step(XEbuf, S1, XEbuf, Wg1w, Wcx1w, Wcs1w, bg1r, bg1u, bc1w, uw, t);
        layer_step(S1,    S2, XEbuf, Wg2w, Wcx2w, Wcs2w, bg2r, bg2u, bc2w, uw, t);
    }

    // ---------- head: h = relu(S2@Wo1+bo1) (into XEbuf), then y quarter ----------
    float hq[16];
    const float* bo1w = bo1 + uw * 16;
    #pragma unroll
    for (int j = 0; j < 16; j++) hq[j] = bo1w[j];
    #pragma unroll 1
    for (int kc = 0; kc < 8; kc++) {
        float sv[8];
        #pragma unroll
        for (int i = 0; i < 8; i++) sv[i] = S2[(kc * 8 + i) * 64 + t];
        #pragma unroll
        for (int i = 0; i < 8; i++) {
            const float* wk = Wo1w + (kc * 8 + i) * 16;
            #pragma unroll
            for (int j = 0; j < 16; j++) hq[j] = fmaf(sv[i], wk[j], hq[j]);
        }
    }
    #pragma unroll
    for (int j = 0; j < 16; j++) XEbuf[(uw * 16 + j) * 64 + t] = fmaxf(hq[j], 0.0f);
    __syncthreads();
    float y0 = bo2[3 * uw], y1 = bo2[3 * uw + 1], y2 = bo2[3 * uw + 2];
    #pragma unroll 4
    for (int j = 0; j < 64; j++) {
        const float hj = XEbuf[j * 64 + t];
        y0 = fmaf(hj, Wo2[j * 12 + 3 * uw + 0], y0);
        y1 = fmaf(hj, Wo2[j * 12 + 3 * uw + 1], y1);
        y2 = fmaf(hj, Wo2[j * 12 + 3 * uw + 2], y2);
    }
    out[(b * 12 + 3 * uw + 0) * NB + n] = y0;
    out[(b * 12 + 3 * uw + 1) * NB + n] = y1;
    out[(b * 12 + 3 * uw + 2) * NB + n] = y2;
}

extern "C" void kernel_launch(void* const* d_in, const int* in_sizes, int n_in,
                              void* d_out, int out_size, void* d_ws, size_t ws_size,
                              hipStream_t stream) {
    const float* X    = (const float*)d_in[0];
    // d_in[1]=ZC, d_in[2]=ZF unused by the reference
    const float* SE   = (const float*)d_in[3];
    const float* Wse1 = (const float*)d_in[4];
    const float* bse1 = (const float*)d_in[5];
    const float* Wse2 = (const float*)d_in[6];
    const float* bse2 = (const float*)d_in[7];
    const float* Wte1 = (const float*)d_in[8];
    const float* bte1 = (const float*)d_in[9];
    const float* Wte2 = (const float*)d_in[10];
    const float* bte2 = (const float*)d_in[11];
    const float* Win1 = (const float*)d_in[12];
    const float* bin1 = (const float*)d_in[13];
    const float* Win2 = (const float*)d_in[14];
    const float* bin2 = (const float*)d_in[15];
    const float* Wg1  = (const float*)d_in[16];
    const float* bg1  = (const float*)d_in[17];
    const float* Wc1  = (const float*)d_in[18];
    const float* bc1  = (const float*)d_in[19];
    const float* Wg2  = (const float*)d_in[20];
    const float* bg2  = (const float*)d_in[21];
    const float* Wc2  = (const float*)d_in[22];
    const float* bc2  = (const float*)d_in[23];
    const float* Wo1  = (const float*)d_in[24];
    const float* bo1  = (const float*)d_in[25];
    const float* Wo2  = (const float*)d_in[26];
    const float* bo2  = (const float*)d_in[27];
    const int*   TE   = (const int*)d_in[28];

    float* ws  = (float*)d_ws;                 // 172032 floats = 688 KB
    float* seT = ws + 57344;
    float* teo = ws + 122880;
    float* out = (float*)d_out;

    prep_all<<<224, 256, 0, stream>>>(Wg1, Wc1, Wg2, Wc2, Win2, Wo1, ws);
    prep_se<<<1024, 64, 0, stream>>>(SE, Wse1, bse1, Wse2, bse2, bin2, seT);
    prep_te<<<768, 64, 0, stream>>>(TE, Wte1, bte1, Wte2, bte2, teo);
    gman_main<<<1024, 256, 0, stream>>>(X, ws, Win1, bin1, bg1, bc1, bg2, bc2,
                                        bo1, Wo2, bo2, out);
}

// Round 6
// 669.447 us; speedup vs baseline: 10.9208x; 2.2467x over previous
//
#include <hip/hip_runtime.h>

// GMAN pipeline, fully fused, MFMA edition. support = I -> per-block token GEMMs.
// B=64, P=Q=12, N=1024, D=64. Output [B,Q,N] fp32.
//
// R6: fp32 VALU path plateaued at ~78% of its 538us floor (R5: 1504us, VALU 45%).
// Rewrite all GEMMs as mfma_f32_16x16x32_bf16 with 3-product split emulation
// (A=Ahi+Alo, B=Bhi+Blo, drop AloBlo: rel err ~2^-16).
//  - block = 256 thr = 4 waves, 64 tokens (M=64 -> 4 m-tiles/wave), N-split by wave.
//  - activations XE/S1/S2/RS in LDS [64][64] fp32, XOR-8 swizzle (k ^ ((t&3)<<3)):
//    64 KB exact, b128 A-frag reads bank-even, C-writes consistent (xor bits 3-4 only).
//  - weights pre-split hi/lo and packed in per-lane B-frag order by prep kernels:
//    lane l holds B[k0+(l>>4)*8+j][n0+(l&15)] -> one dwordx4 per frag-half, coalesced.
//  - A-frag: m = l&15 (+16*mt), k = k0+(l>>4)*8+j ; C/D: row=(l>>4)*4+reg, col=l&15.

#define NB 1024

typedef float f32x4 __attribute__((ext_vector_type(4)));
typedef __bf16 bf16x8 __attribute__((ext_vector_type(8)));
typedef int i32x4 __attribute__((ext_vector_type(4)));

#define MFMA(a, b, c) __builtin_amdgcn_mfma_f32_16x16x32_bf16(a, b, c, 0, 0, 0)

__device__ __forceinline__ float fexp(float x) {
    return __builtin_amdgcn_exp2f(x * 1.44269504088896341f);
}
__device__ __forceinline__ float fsigmoid(float x) {
    return __builtin_amdgcn_rcpf(1.0f + fexp(-x));
}
__device__ __forceinline__ float ftanh(float x) {
    return 1.0f - 2.0f * __builtin_amdgcn_rcpf(1.0f + fexp(2.0f * x));
}

__device__ __forceinline__ bf16x8 ldfrag(const unsigned short* p) {
    i32x4 t = *(const i32x4*)p;
    return __builtin_bit_cast(bf16x8, t);
}
__device__ __forceinline__ void split8(f32x4 a0, f32x4 a1, bf16x8& hi, bf16x8& lo) {
    #pragma unroll
    for (int i = 0; i < 4; i++) {
        __bf16 h0 = (__bf16)a0[i]; hi[i] = h0;     lo[i] = (__bf16)(a0[i] - (float)h0);
        __bf16 h1 = (__bf16)a1[i]; hi[4 + i] = h1; lo[4 + i] = (__bf16)(a1[i] - (float)h1);
    }
}
__device__ __forceinline__ void wsplit(float v, unsigned short* dhi, unsigned short* dlo) {
    __bf16 h = (__bf16)v;
    __bf16 l = (__bf16)(v - (float)h);
    *dhi = __builtin_bit_cast(unsigned short, h);
    *dlo = __builtin_bit_cast(unsigned short, l);
}

// ---------------- ws layout (dwords) ----------------
// 0      FR_G1 gates L1 frags [w][nt][ks][half][lane][8bf16]  16384 dw
// 16384  FR_G2
// 32768  FR_C1 cand L1 [w][ks][half][lane][8]                  8192 dw
// 40960  FR_C2
// 49152  FR_XE Win2 [w][ks(2)][half][lane][8]                  4096 dw
// 53248  FR_HD Wo1                                             4096 dw
// 57344  seW [n][d] fp32 (b_in2 folded)                       65536 dw
// 122880 teo [768][64] fp32                                   49152 dw

// gates combined: Wg_comb[k][col] = Wg[k*128+col] + Wg[(k+128)*128+col], k in [0,128)
__global__ void prep_gates(const float* __restrict__ Wg1, const float* __restrict__ Wg2,
                           unsigned short* __restrict__ fr) {
    int i = blockIdx.x * 256 + threadIdx.x;            // [0, 4096)
    if (i >= 4096) return;
    int layer = i >> 11, r = i & 2047;
    int w = r >> 9; r &= 511; int nt = r >> 8; r &= 255; int ks = r >> 6; int lane = r & 63;
    const float* Wg = layer ? Wg2 : Wg1;
    int n = lane & 15, q = lane >> 4;
    int col = nt ? (64 + w * 16 + n) : (w * 16 + n);
    unsigned short* dst = fr + layer * 32768 + (((w * 2 + nt) * 4 + ks) * 2) * 512 + lane * 8;
    #pragma unroll
    for (int j = 0; j < 8; j++) {
        int k = ks * 32 + q * 8 + j;
        float v = Wg[k * 128 + col] + Wg[(k + 128) * 128 + col];
        wsplit(v, dst + j, dst + 512 + j);
    }
}

// cand combined: Wc_comb[k][col] = Wc[k*64+col] + Wc[(k+128)*64+col], k in [0,128)
__global__ void prep_cand(const float* __restrict__ Wc1, const float* __restrict__ Wc2,
                          unsigned short* __restrict__ fr) {
    int i = blockIdx.x * 256 + threadIdx.x;            // [0, 2048)
    if (i >= 2048) return;
    int layer = i >> 10, r = i & 1023;
    int w = r >> 8; r &= 255; int ks = r >> 6; int lane = r & 63;
    const float* Wc = layer ? Wc2 : Wc1;
    int n = lane & 15, q = lane >> 4;
    int col = w * 16 + n;
    unsigned short* dst = fr + 65536 + layer * 16384 + ((w * 4 + ks) * 2) * 512 + lane * 8;
    #pragma unroll
    for (int j = 0; j < 8; j++) {
        int k = ks * 32 + q * 8 + j;
        float v = Wc[k * 64 + col] + Wc[(k + 128) * 64 + col];
        wsplit(v, dst + j, dst + 512 + j);
    }
}

// xe (Win2) + head (Wo1): plain [64][64] matrices
__global__ void prep_small(const float* __restrict__ Win2, const float* __restrict__ Wo1,
                           unsigned short* __restrict__ fr) {
    int i = blockIdx.x * 256 + threadIdx.x;            // [0, 1024)
    if (i >= 1024) return;
    int kind = i >> 9, r = i & 511;
    int w = r >> 7; r &= 127; int ks = r >> 6; int lane = r & 63;
    const float* W = kind ? Wo1 : Win2;
    int n = lane & 15, q = lane >> 4;
    int col = w * 16 + n;
    unsigned short* dst = fr + 98304 + kind * 8192 + ((w * 2 + ks) * 2) * 512 + lane * 8;
    #pragma unroll
    for (int j = 0; j < 8; j++) {
        int k = ks * 32 + q * 8 + j;
        float v = W[k * 64 + col];
        wsplit(v, dst + j, dst + 512 + j);
    }
}

// se = relu(SE@W1+b1)@W2+b2, natural [n][d], b_in2 folded in.
__global__ void prep_se(const float* __restrict__ SE, const float* __restrict__ W1,
                        const float* __restrict__ b1, const float* __restrict__ W2,
                        const float* __restrict__ b2, const float* __restrict__ bin2,
                        float* __restrict__ seW) {
    __shared__ float h[64];
    int n = blockIdx.x, d = threadIdx.x;
    float acc = b1[d];
    for (int k = 0; k < 64; k++) acc = fmaf(SE[n * 64 + k], W1[k * 64 + d], acc);
    h[d] = fmaxf(acc, 0.0f);
    __syncthreads();
    float acc2 = b2[d];
    for (int k = 0; k < 64; k++) acc2 = fmaf(h[k], W2[k * 64 + d], acc2);
    seW[n * 64 + d] = acc2 + bin2[d];
}

__global__ void prep_te(const int* __restrict__ TE, const float* __restrict__ W1,
                        const float* __restrict__ b1, const float* __restrict__ W2,
                        const float* __restrict__ b2, float* __restrict__ teo) {
    __shared__ float h[64];
    int bp = blockIdx.x;
    int b = bp / 12, p = bp - b * 12;
    int d = threadIdx.x;
    int dow = TE[(b * 24 + p) * 2 + 0];
    int tod = TE[(b * 24 + p) * 2 + 1];
    float v = W1[dow * 64 + d] + W1[(7 + tod) * 64 + d] + b1[d];
    h[d] = fmaxf(v, 0.0f);
    __syncthreads();
    float acc = b2[d];
    for (int k = 0; k < 64; k++) acc = fmaf(h[k], W2[k * 64 + d], acc);
    teo[bp * 64 + d] = acc;
}

#define SW(t, k) ((t) * 64 + ((k) ^ (((t) & 3) << 3)))

// one GRU step. XIN/S/RS are distinct LDS buffers. Wave w owns cols [16w,16w+16).
__device__ __forceinline__ void gru_layer(
    const float* __restrict__ XIN, float* __restrict__ S, float* __restrict__ RS,
    const unsigned short* __restrict__ frG, const unsigned short* __restrict__ frC,
    const float* __restrict__ bg, const float* __restrict__ bc, int l, int w) {
    const int n16 = l & 15, q = l >> 4;
    const int col = w * 16 + n16;
    f32x4 accR[4], accU[4];
    #pragma unroll
    for (int mt = 0; mt < 4; mt++) { accR[mt] = (f32x4)0.0f; accU[mt] = (f32x4)0.0f; }
    // ---- gates: A = [XIN(k<64) | S(k>=64)], B = wave's 16 r-cols + 16 u-cols ----
    #pragma unroll
    for (int ks = 0; ks < 4; ks++) {
        bf16x8 bhiR = ldfrag(frG + ((0 * 4 + ks) * 2 + 0) * 512 + l * 8);
        bf16x8 bloR = ldfrag(frG + ((0 * 4 + ks) * 2 + 1) * 512 + l * 8);
        bf16x8 bhiU = ldfrag(frG + ((1 * 4 + ks) * 2 + 0) * 512 + l * 8);
        bf16x8 bloU = ldfrag(frG + ((1 * 4 + ks) * 2 + 1) * 512 + l * 8);
        const float* src = (ks < 2) ? XIN : S;
        const int kk = (ks * 32 + q * 8) & 63;
        #pragma unroll
        for (int mt = 0; mt < 4; mt++) {
            const int m = mt * 16 + n16;
            const float* ap = src + m * 64 + (kk ^ ((m & 3) << 3));
            f32x4 a0 = *(const f32x4*)ap, a1 = *(const f32x4*)(ap + 4);
            bf16x8 ahi, alo; split8(a0, a1, ahi, alo);
            accR[mt] = MFMA(ahi, bhiR, accR[mt]);
            accR[mt] = MFMA(alo, bhiR, accR[mt]);
            accR[mt] = MFMA(ahi, bloR, accR[mt]);
            accU[mt] = MFMA(ahi, bhiU, accU[mt]);
            accU[mt] = MFMA(alo, bhiU, accU[mt]);
            accU[mt] = MFMA(ahi, bloU, accU[mt]);
        }
    }
    // ---- rs = sigmoid(r) * s  (C-layout elementwise; wave writes its 16 cols) ----
    const float bgr = bg[col];
    #pragma unroll
    for (int mt = 0; mt < 4; mt++)
        #pragma unroll
        for (int r = 0; r < 4; r++) {
            int tok = mt * 16 + q * 4 + r;
            float rs = fsigmoid(accR[mt][r] + bgr) * S[SW(tok, col)];
            RS[SW(tok, col)] = rs;
        }
    __syncthreads();   // rs visible to all waves
    // ---- candidate: A = [XIN(k<64) | RS(k>=64)], B = wave's 16 cand cols ----
    f32x4 accC[4];
    #pragma unroll
    for (int mt = 0; mt < 4; mt++) accC[mt] = (f32x4)0.0f;
    #pragma unroll
    for (int ks = 0; ks < 4; ks++) {
        bf16x8 bhi = ldfrag(frC + (ks * 2 + 0) * 512 + l * 8);
        bf16x8 blo = ldfrag(frC + (ks * 2 + 1) * 512 + l * 8);
        const float* src = (ks < 2) ? XIN : RS;
        const int kk = (ks * 32 + q * 8) & 63;
        #pragma unroll
        for (int mt = 0; mt < 4; mt++) {
            const int m = mt * 16 + n16;
            const float* ap = src + m * 64 + (kk ^ ((m & 3) << 3));
            f32x4 a0 = *(const f32x4*)ap, a1 = *(const f32x4*)(ap + 4);
            bf16x8 ahi, alo; split8(a0, a1, ahi, alo);
            accC[mt] = MFMA(ahi, bhi, accC[mt]);
            accC[mt] = MFMA(alo, bhi, accC[mt]);
            accC[mt] = MFMA(ahi, blo, accC[mt]);
        }
    }
    // ---- state update (each (tok,col) owned by exactly one lane) ----
    const float bcc = bc[col], bgu = bg[64 + col];
    #pragma unroll
    for (int mt = 0; mt < 4; mt++)
        #pragma unroll
        for (int r = 0; r < 4; r++) {
            int tok = mt * 16 + q * 4 + r;
            float u = fsigmoid(accU[mt][r] + bgu);
            float cnd = ftanh(accC[mt][r] + bcc);
            int a = SW(tok, col);
            S[a] = u * S[a] + (1.0f - u) * cnd;
        }
    __syncthreads();   // state visible
}

__global__ __launch_bounds__(256, 2) void gman_main(
    const float* __restrict__ X, const float* __restrict__ ws,
    const float* __restrict__ Win1, const float* __restrict__ bin1,
    const float* __restrict__ bg1, const float* __restrict__ bc1,
    const float* __restrict__ bg2, const float* __restrict__ bc2,
    const float* __restrict__ bo1, const float* __restrict__ Wo2,
    const float* __restrict__ bo2, float* __restrict__ out) {
    __shared__ float XE[4096], S1[4096], S2[4096], RS[4096];   // 64 KB exact

    const int tid = threadIdx.x;
    const int l = tid & 63;
    const int w = tid >> 6;
    const int n16 = l & 15, q = l >> 4;
    const int col = w * 16 + n16;
    const int b = blockIdx.x >> 4;
    const int n0 = (blockIdx.x & 15) << 6;

    const unsigned short* frU = (const unsigned short*)ws;
    const unsigned short* frG1 = frU + w * 8192;
    const unsigned short* frG2 = frU + 32768 + w * 8192;
    const unsigned short* frC1 = frU + 65536 + w * 4096;
    const unsigned short* frC2 = frU + 81920 + w * 4096;
    const unsigned short* frX  = frU + 98304 + w * 2048;
    const unsigned short* frH  = frU + 106496 + w * 2048;
    const float* seW = ws + 57344;
    const float* teo = ws + 122880;

    #pragma unroll
    for (int i = 0; i < 16; i++) { S1[tid + i * 256] = 0.0f; S2[tid + i * 256] = 0.0f; }

    #pragma unroll 1
    for (int p = 0; p < 12; p++) {
        // ---- stage x into RS[0..63] (RS free here) ----
        if (tid < 64) RS[tid] = X[(b * 12 + p) * NB + n0 + tid];
        __syncthreads();
        // ---- xe GEMM: A = h1 (VALU-built), B = Win2 quarter ----
        f32x4 accX[4];
        #pragma unroll
        for (int mt = 0; mt < 4; mt++) accX[mt] = (f32x4)0.0f;
        #pragma unroll
        for (int ks = 0; ks < 2; ks++) {
            const int k0 = ks * 32 + q * 8;
            f32x4 w1a = *(const f32x4*)(Win1 + k0), w1b = *(const f32x4*)(Win1 + k0 + 4);
            f32x4 b1a = *(const f32x4*)(bin1 + k0), b1b = *(const f32x4*)(bin1 + k0 + 4);
            bf16x8 bhi = ldfrag(frX + (ks * 2 + 0) * 512 + l * 8);
            bf16x8 blo = ldfrag(frX + (ks * 2 + 1) * 512 + l * 8);
            #pragma unroll
            for (int mt = 0; mt < 4; mt++) {
                const float xm = RS[mt * 16 + n16];
                f32x4 h0, h1v;
                #pragma unroll
                for (int i = 0; i < 4; i++) {
                    h0[i]  = fmaxf(fmaf(xm, w1a[i], b1a[i]), 0.0f);
                    h1v[i] = fmaxf(fmaf(xm, w1b[i], b1b[i]), 0.0f);
                }
                bf16x8 ahi, alo; split8(h0, h1v, ahi, alo);
                accX[mt] = MFMA(ahi, bhi, accX[mt]);
                accX[mt] = MFMA(alo, bhi, accX[mt]);
                accX[mt] = MFMA(ahi, blo, accX[mt]);
            }
        }
        const float tev = teo[(b * 12 + p) * 64 + col];
        #pragma unroll
        for (int mt = 0; mt < 4; mt++)
            #pragma unroll
            for (int r = 0; r < 4; r++) {
                int tok = mt * 16 + q * 4 + r;
                XE[SW(tok, col)] = accX[mt][r] + seW[(n0 + tok) * 64 + col] + tev;
            }
        __syncthreads();   // XE complete

        gru_layer(XE, S1, RS, frG1, frC1, bg1, bc1, l, w);
        gru_layer(S1, S2, RS, frG2, frC2, bg2, bc2, l, w);
    }

    // ---- head: h = relu(S2@Wo1+bo1) via MFMA (into XE), then tiny y GEMV ----
    f32x4 accH[4];
    #pragma unroll
    for (int mt = 0; mt < 4; mt++) accH[mt] = (f32x4)0.0f;
    #pragma unroll
    for (int ks = 0; ks < 2; ks++) {
        bf16x8 bhi = ldfrag(frH + (ks * 2 + 0) * 512 + l * 8);
        bf16x8 blo = ldfrag(frH + (ks * 2 + 1) * 512 + l * 8);
        const int kk = ks * 32 + q * 8;
        #pragma unroll
        for (int mt = 0; mt < 4; mt++) {
            const int m = mt * 16 + n16;
            const float* ap = S2 + m * 64 + (kk ^ ((m & 3) << 3));
            f32x4 a0 = *(const f32x4*)ap, a1 = *(const f32x4*)(ap + 4);
            bf16x8 ahi, alo; split8(a0, a1, ahi, alo);
            accH[mt] = MFMA(ahi, bhi, accH[mt]);
            accH[mt] = MFMA(alo, bhi, accH[mt]);
            accH[mt] = MFMA(ahi, blo, accH[mt]);
        }
    }
    const float bo = bo1[col];
    #pragma unroll
    for (int mt = 0; mt < 4; mt++)
        #pragma unroll
        for (int r = 0; r < 4; r++) {
            int tok = mt * 16 + q * 4 + r;
            XE[SW(tok, col)] = fmaxf(accH[mt][r] + bo, 0.0f);
        }
    __syncthreads();
    // y: lane = token, wave owns 3 of the 12 q-cols
    const int uw = __builtin_amdgcn_readfirstlane(w);
    float y0 = bo2[3 * uw], y1 = bo2[3 * uw + 1], y2 = bo2[3 * uw + 2];
    #pragma unroll 8
    for (int j = 0; j < 64; j++) {
        const float hj = XE[SW(l, j)];
        y0 = fmaf(hj, Wo2[j * 12 + 3 * uw + 0], y0);
        y1 = fmaf(hj, Wo2[j * 12 + 3 * uw + 1], y1);
        y2 = fmaf(hj, Wo2[j * 12 + 3 * uw + 2], y2);
    }
    out[(b * 12 + 3 * uw + 0) * NB + n0 + l] = y0;
    out[(b * 12 + 3 * uw + 1) * NB + n0 + l] = y1;
    out[(b * 12 + 3 * uw + 2) * NB + n0 + l] = y2;
}

extern "C" void kernel_launch(void* const* d_in, const int* in_sizes, int n_in,
                              void* d_out, int out_size, void* d_ws, size_t ws_size,
                              hipStream_t stream) {
    const float* X    = (const float*)d_in[0];
    // d_in[1]=ZC, d_in[2]=ZF unused by the reference
    const float* SE   = (const float*)d_in[3];
    const float* Wse1 = (const float*)d_in[4];
    const float* bse1 = (const float*)d_in[5];
    const float* Wse2 = (const float*)d_in[6];
    const float* bse2 = (const float*)d_in[7];
    const float* Wte1 = (const float*)d_in[8];
    const float* bte1 = (const float*)d_in[9];
    const float* Wte2 = (const float*)d_in[10];
    const float* bte2 = (const float*)d_in[11];
    const float* Win1 = (const float*)d_in[12];
    const float* bin1 = (const float*)d_in[13];
    const float* Win2 = (const float*)d_in[14];
    const float* bin2 = (const float*)d_in[15];
    const float* Wg1  = (const float*)d_in[16];
    const float* bg1  = (const float*)d_in[17];
    const float* Wc1  = (const float*)d_in[18];
    const float* bc1  = (const float*)d_in[19];
    const float* Wg2  = (const float*)d_in[20];
    const float* bg2  = (const float*)d_in[21];
    const float* Wc2  = (const float*)d_in[22];
    const float* bc2  = (const float*)d_in[23];
    const float* Wo1  = (const float*)d_in[24];
    const float* bo1  = (const float*)d_in[25];
    const float* Wo2  = (const float*)d_in[26];
    const float* bo2  = (const float*)d_in[27];
    const int*   TE   = (const int*)d_in[28];

    float* ws = (float*)d_ws;                  // 172032 floats = 688 KB
    unsigned short* fr = (unsigned short*)ws;
    float* seW = ws + 57344;
    float* teo = ws + 122880;
    float* out = (float*)d_out;

    prep_gates<<<16, 256, 0, stream>>>(Wg1, Wg2, fr);
    prep_cand<<<8, 256, 0, stream>>>(Wc1, Wc2, fr);
    prep_small<<<4, 256, 0, stream>>>(Win2, Wo1, fr);
    prep_se<<<1024, 64, 0, stream>>>(SE, Wse1, bse1, Wse2, bse2, bin2, seW);
    prep_te<<<768, 64, 0, stream>>>(TE, Wte1, bte1, Wte2, bte2, teo);
    gman_main<<<1024, 256, 0, stream>>>(X, ws, Win1, bin1, bg1, bc1, bg2, bc2,
                                        bo1, Wo2, bo2, out);
}

// Round 7
// 580.171 us; speedup vs baseline: 12.6013x; 1.1539x over previous
//
#include <hip/hip_runtime.h>

// GMAN pipeline, fully fused, MFMA edition. support = I -> per-block token GEMMs.
// B=64, P=Q=12, N=1024, D=64. Output [B,Q,N] fp32.
//
// R7: R6 hit 597us but SQ_LDS_BANK_CONFLICT=9.4e7 (~25% of runtime). Root cause:
// row stride 64 dw == 0 mod 32 banks, and XOR-8 swizzle only spread k over
// {0,8,16,24} -> 16 lanes per 4-bank group (2x over optimal).
//  - SW(t,k) = t*64 + (k ^ ((t&3)<<3) ^ (t&4)): 4-granular, even 8-lane spread
//    over all 8 aligned 4-dword offsets; bits 0-1 untouched so b128 legal
//    (second half-window sits at ^4, computed explicitly).
//  - cand's XIN K-half folded into the gates ks 0..1 pass (one split feeds
//    R+U+C): -25% LDS b128 reads, -25% split VALU per layer.
//  - seB: per-lane-ordered se table -> 4 coalesced dwordx4 loads per p-step.

#define NB 1024

typedef float f32x4 __attribute__((ext_vector_type(4)));
typedef __bf16 bf16x8 __attribute__((ext_vector_type(8)));
typedef int i32x4 __attribute__((ext_vector_type(4)));

#define MFMA(a, b, c) __builtin_amdgcn_mfma_f32_16x16x32_bf16(a, b, c, 0, 0, 0)

__device__ __forceinline__ float fexp(float x) {
    return __builtin_amdgcn_exp2f(x * 1.44269504088896341f);
}
__device__ __forceinline__ float fsigmoid(float x) {
    return __builtin_amdgcn_rcpf(1.0f + fexp(-x));
}
__device__ __forceinline__ float ftanh(float x) {
    return 1.0f - 2.0f * __builtin_amdgcn_rcpf(1.0f + fexp(2.0f * x));
}

__device__ __forceinline__ bf16x8 ldfrag(const unsigned short* p) {
    i32x4 t = *(const i32x4*)p;
    return __builtin_bit_cast(bf16x8, t);
}
__device__ __forceinline__ void split8(f32x4 a0, f32x4 a1, bf16x8& hi, bf16x8& lo) {
    #pragma unroll
    for (int i = 0; i < 4; i++) {
        __bf16 h0 = (__bf16)a0[i]; hi[i] = h0;     lo[i] = (__bf16)(a0[i] - (float)h0);
        __bf16 h1 = (__bf16)a1[i]; hi[4 + i] = h1; lo[4 + i] = (__bf16)(a1[i] - (float)h1);
    }
}
__device__ __forceinline__ void wsplit(float v, unsigned short* dhi, unsigned short* dlo) {
    __bf16 h = (__bf16)v;
    __bf16 l = (__bf16)(v - (float)h);
    *dhi = __builtin_bit_cast(unsigned short, h);
    *dlo = __builtin_bit_cast(unsigned short, l);
}

// ---------------- ws layout (dwords) ----------------
// 0      FR_G1 gates L1 frags [w][nt][ks][half][lane][8bf16]  16384 dw
// 16384  FR_G2
// 32768  FR_C1 cand L1 [w][ks][half][lane][8]                  8192 dw
// 40960  FR_C2
// 49152  FR_XE Win2 [w][ks(2)][half][lane][8]                  4096 dw
// 53248  FR_HD Wo1                                             4096 dw
// 57344  seB [nb][w][lane][16] fp32 (b_in2 folded)            65536 dw
// 122880 teo [768][64] fp32                                   49152 dw

__global__ void prep_gates(const float* __restrict__ Wg1, const float* __restrict__ Wg2,
                           unsigned short* __restrict__ fr) {
    int i = blockIdx.x * 256 + threadIdx.x;            // [0, 4096)
    if (i >= 4096) return;
    int layer = i >> 11, r = i & 2047;
    int w = r >> 9; r &= 511; int nt = r >> 8; r &= 255; int ks = r >> 6; int lane = r & 63;
    const float* Wg = layer ? Wg2 : Wg1;
    int n = lane & 15, q = lane >> 4;
    int col = nt ? (64 + w * 16 + n) : (w * 16 + n);
    unsigned short* dst = fr + layer * 32768 + (((w * 2 + nt) * 4 + ks) * 2) * 512 + lane * 8;
    #pragma unroll
    for (int j = 0; j < 8; j++) {
        int k = ks * 32 + q * 8 + j;
        float v = Wg[k * 128 + col] + Wg[(k + 128) * 128 + col];
        wsplit(v, dst + j, dst + 512 + j);
    }
}

__global__ void prep_cand(const float* __restrict__ Wc1, const float* __restrict__ Wc2,
                          unsigned short* __restrict__ fr) {
    int i = blockIdx.x * 256 + threadIdx.x;            // [0, 2048)
    if (i >= 2048) return;
    int layer = i >> 10, r = i & 1023;
    int w = r >> 8; r &= 255; int ks = r >> 6; int lane = r & 63;
    const float* Wc = layer ? Wc2 : Wc1;
    int n = lane & 15, q = lane >> 4;
    int col = w * 16 + n;
    unsigned short* dst = fr + 65536 + layer * 16384 + ((w * 4 + ks) * 2) * 512 + lane * 8;
    #pragma unroll
    for (int j = 0; j < 8; j++) {
        int k = ks * 32 + q * 8 + j;
        float v = Wc[k * 64 + col] + Wc[(k + 128) * 64 + col];
        wsplit(v, dst + j, dst + 512 + j);
    }
}

__global__ void prep_small(const float* __restrict__ Win2, const float* __restrict__ Wo1,
                           unsigned short* __restrict__ fr) {
    int i = blockIdx.x * 256 + threadIdx.x;            // [0, 1024)
    if (i >= 1024) return;
    int kind = i >> 9, r = i & 511;
    int w = r >> 7; r &= 127; int ks = r >> 6; int lane = r & 63;
    const float* W = kind ? Wo1 : Win2;
    int n = lane & 15, q = lane >> 4;
    int col = w * 16 + n;
    unsigned short* dst = fr + 98304 + kind * 8192 + ((w * 2 + ks) * 2) * 512 + lane * 8;
    #pragma unroll
    for (int j = 0; j < 8; j++) {
        int k = ks * 32 + q * 8 + j;
        float v = W[k * 64 + col];
        wsplit(v, dst + j, dst + 512 + j);
    }
}

// se = relu(SE@W1+b1)@W2+b2 + b_in2, stored lane-ordered:
// seB[((nb*4 + w)*64 + q*16 + n16)*16 + mt*4 + r] for n = nb*64 + mt*16 + q*4 + r, d = w*16+n16
__global__ void prep_se(const float* __restrict__ SE, const float* __restrict__ W1,
                        const float* __restrict__ b1, const float* __restrict__ W2,
                        const float* __restrict__ b2, const float* __restrict__ bin2,
                        float* __restrict__ seB) {
    __shared__ float h[64];
    int n = blockIdx.x, d = threadIdx.x;
    float acc = b1[d];
    for (int k = 0; k < 64; k++) acc = fmaf(SE[n * 64 + k], W1[k * 64 + d], acc);
    h[d] = fmaxf(acc, 0.0f);
    __syncthreads();
    float acc2 = b2[d];
    for (int k = 0; k < 64; k++) acc2 = fmaf(h[k], W2[k * 64 + d], acc2);
    int nb = n >> 6, tok = n & 63;
    int mt = tok >> 4, q = (tok >> 2) & 3, r = tok & 3;
    int w = d >> 4, n16 = d & 15;
    seB[(((nb * 4 + w) * 64) + q * 16 + n16) * 16 + mt * 4 + r] = acc2 + bin2[d];
}

__global__ void prep_te(const int* __restrict__ TE, const float* __restrict__ W1,
                        const float* __restrict__ b1, const float* __restrict__ W2,
                        const float* __restrict__ b2, float* __restrict__ teo) {
    __shared__ float h[64];
    int bp = blockIdx.x;
    int b = bp / 12, p = bp - b * 12;
    int d = threadIdx.x;
    int dow = TE[(b * 24 + p) * 2 + 0];
    int tod = TE[(b * 24 + p) * 2 + 1];
    float v = W1[dow * 64 + d] + W1[(7 + tod) * 64 + d] + b1[d];
    h[d] = fmaxf(v, 0.0f);
    __syncthreads();
    float acc = b2[d];
    for (int k = 0; k < 64; k++) acc = fmaf(h[k], W2[k * 64 + d], acc);
    teo[bp * 64 + d] = acc;
}

// 4-granular swizzle: bits 0-1 of k untouched (b128 legal), banks evenly spread.
#define SW(t, k) ((t) * 64 + ((k) ^ (((t) & 3) << 3) ^ ((t) & 4)))

// read A-frag (8 k-values from swizzled row m, k0 8-aligned) and 3-split it
__device__ __forceinline__ void lda_split(const float* __restrict__ src, int m, int k0,
                                          bf16x8& ahi, bf16x8& alo) {
    const int sk = (k0 ^ ((m & 3) << 3) ^ (m & 4));
    f32x4 a0 = *(const f32x4*)(src + m * 64 + sk);
    f32x4 a1 = *(const f32x4*)(src + m * 64 + (sk ^ 4));
    split8(a0, a1, ahi, alo);
}

// one GRU step. Wave w owns cols [16w,16w+16).
__device__ __forceinline__ void gru_layer(
    const float* __restrict__ XIN, float* __restrict__ S, float* __restrict__ RS,
    const unsigned short* __restrict__ frG, const unsigned short* __restrict__ frC,
    const float* __restrict__ bg, const float* __restrict__ bc, int l, int w) {
    const int n16 = l & 15, q = l >> 4;
    const int col = w * 16 + n16;
    f32x4 accR[4], accU[4], accC[4];
    #pragma unroll
    for (int mt = 0; mt < 4; mt++) {
        accR[mt] = (f32x4)0.0f; accU[mt] = (f32x4)0.0f; accC[mt] = (f32x4)0.0f;
    }
    // ---- phase 1: ks 0..1 (XIN K-half): one split feeds R + U + C ----
    #pragma unroll
    for (int ks = 0; ks < 2; ks++) {
        bf16x8 bhiR = ldfrag(frG + ((0 * 4 + ks) * 2 + 0) * 512 + l * 8);
        bf16x8 bloR = ldfrag(frG + ((0 * 4 + ks) * 2 + 1) * 512 + l * 8);
        bf16x8 bhiU = ldfrag(frG + ((1 * 4 + ks) * 2 + 0) * 512 + l * 8);
        bf16x8 bloU = ldfrag(frG + ((1 * 4 + ks) * 2 + 1) * 512 + l * 8);
        bf16x8 bhiC = ldfrag(frC + (ks * 2 + 0) * 512 + l * 8);
        bf16x8 bloC = ldfrag(frC + (ks * 2 + 1) * 512 + l * 8);
        const int kk = ks * 32 + q * 8;
        #pragma unroll
        for (int mt = 0; mt < 4; mt++) {
            bf16x8 ahi, alo;
            lda_split(XIN, mt * 16 + n16, kk, ahi, alo);
            accR[mt] = MFMA(ahi, bhiR, accR[mt]);
            accR[mt] = MFMA(alo, bhiR, accR[mt]);
            accR[mt] = MFMA(ahi, bloR, accR[mt]);
            accU[mt] = MFMA(ahi, bhiU, accU[mt]);
            accU[mt] = MFMA(alo, bhiU, accU[mt]);
            accU[mt] = MFMA(ahi, bloU, accU[mt]);
            accC[mt] = MFMA(ahi, bhiC, accC[mt]);
            accC[mt] = MFMA(alo, bhiC, accC[mt]);
            accC[mt] = MFMA(ahi, bloC, accC[mt]);
        }
    }
    // ---- phase 2: ks 2..3 (S K-half): gates only ----
    #pragma unroll
    for (int ks = 2; ks < 4; ks++) {
        bf16x8 bhiR = ldfrag(frG + ((0 * 4 + ks) * 2 + 0) * 512 + l * 8);
        bf16x8 bloR = ldfrag(frG + ((0 * 4 + ks) * 2 + 1) * 512 + l * 8);
        bf16x8 bhiU = ldfrag(frG + ((1 * 4 + ks) * 2 + 0) * 512 + l * 8);
        bf16x8 bloU = ldfrag(frG + ((1 * 4 + ks) * 2 + 1) * 512 + l * 8);
        const int kk = (ks - 2) * 32 + q * 8;
        #pragma unroll
        for (int mt = 0; mt < 4; mt++) {
            bf16x8 ahi, alo;
            lda_split(S, mt * 16 + n16, kk, ahi, alo);
            accR[mt] = MFMA(ahi, bhiR, accR[mt]);
            accR[mt] = MFMA(alo, bhiR, accR[mt]);
            accR[mt] = MFMA(ahi, bloR, accR[mt]);
            accU[mt] = MFMA(ahi, bhiU, accU[mt]);
            accU[mt] = MFMA(alo, bhiU, accU[mt]);
            accU[mt] = MFMA(ahi, bloU, accU[mt]);
        }
    }
    // ---- rs = sigmoid(r) * s ----
    const float bgr = bg[col];
    #pragma unroll
    for (int mt = 0; mt < 4; mt++)
        #pragma unroll
        for (int r = 0; r < 4; r++) {
            int tok = mt * 16 + q * 4 + r;
            RS[SW(tok, col)] = fsigmoid(accR[mt][r] + bgr) * S[SW(tok, col)];
        }
    __syncthreads();   // rs visible
    // ---- phase 3: cand ks 2..3 (RS K-half) ----
    #pragma unroll
    for (int ks = 2; ks < 4; ks++) {
        bf16x8 bhi = ldfrag(frC + (ks * 2 + 0) * 512 + l * 8);
        bf16x8 blo = ldfrag(frC + (ks * 2 + 1) * 512 + l * 8);
        const int kk = (ks - 2) * 32 + q * 8;
        #pragma unroll
        for (int mt = 0; mt < 4; mt++) {
            bf16x8 ahi, alo;
            lda_split(RS, mt * 16 + n16, kk, ahi, alo);
            accC[mt] = MFMA(ahi, bhi, accC[mt]);
            accC[mt] = MFMA(alo, bhi, accC[mt]);
            accC[mt] = MFMA(ahi, blo, accC[mt]);
        }
    }
    // ---- state update ----
    const float bcc = bc[col], bgu = bg[64 + col];
    #pragma unroll
    for (int mt = 0; mt < 4; mt++)
        #pragma unroll
        for (int r = 0; r < 4; r++) {
            int tok = mt * 16 + q * 4 + r;
            float u = fsigmoid(accU[mt][r] + bgu);
            float cnd = ftanh(accC[mt][r] + bcc);
            int a = SW(tok, col);
            S[a] = u * S[a] + (1.0f - u) * cnd;
        }
    __syncthreads();   // state visible + RS reads complete
}

__global__ __launch_bounds__(256, 2) void gman_main(
    const float* __restrict__ X, const float* __restrict__ ws,
    const float* __restrict__ Win1, const float* __restrict__ bin1,
    const float* __restrict__ bg1, const float* __restrict__ bc1,
    const float* __restrict__ bg2, const float* __restrict__ bc2,
    const float* __restrict__ bo1, const float* __restrict__ Wo2,
    const float* __restrict__ bo2, float* __restrict__ out) {
    __shared__ float XE[4096], S1[4096], S2[4096], RS[4096];   // 64 KB exact

    const int tid = threadIdx.x;
    const int l = tid & 63;
    const int w = tid >> 6;
    const int n16 = l & 15, q = l >> 4;
    const int col = w * 16 + n16;
    const int b = blockIdx.x >> 4;
    const int nb = blockIdx.x & 15;
    const int n0 = nb << 6;

    const unsigned short* frU = (const unsigned short*)ws;
    const unsigned short* frG1 = frU + w * 8192;
    const unsigned short* frG2 = frU + 32768 + w * 8192;
    const unsigned short* frC1 = frU + 65536 + w * 4096;
    const unsigned short* frC2 = frU + 81920 + w * 4096;
    const unsigned short* frX  = frU + 98304 + w * 2048;
    const unsigned short* frH  = frU + 106496 + w * 2048;
    const float* seQ = ws + 57344 + (((nb * 4 + w) * 64) + l) * 16;
    const float* teo = ws + 122880;

    #pragma unroll
    for (int i = 0; i < 16; i++) { S1[tid + i * 256] = 0.0f; S2[tid + i * 256] = 0.0f; }

    // per-lane se values (p-invariant): se[mt*4+r]
    f32x4 se[4];
    #pragma unroll
    for (int mt = 0; mt < 4; mt++) se[mt] = *(const f32x4*)(seQ + mt * 4);

    #pragma unroll 1
    for (int p = 0; p < 12; p++) {
        // ---- stage x into RS[0..63] raw (RS free here) ----
        if (tid < 64) RS[tid] = X[(b * 12 + p) * NB + n0 + tid];
        __syncthreads();
        // ---- xe GEMM: A = h1 (VALU-built), B = Win2 quarter ----
        f32x4 accX[4];
        #pragma unroll
        for (int mt = 0; mt < 4; mt++) accX[mt] = (f32x4)0.0f;
        #pragma unroll
        for (int ks = 0; ks < 2; ks++) {
            const int k0 = ks * 32 + q * 8;
            f32x4 w1a = *(const f32x4*)(Win1 + k0), w1b = *(const f32x4*)(Win1 + k0 + 4);
            f32x4 b1a = *(const f32x4*)(bin1 + k0), b1b = *(const f32x4*)(bin1 + k0 + 4);
            bf16x8 bhi = ldfrag(frX + (ks * 2 + 0) * 512 + l * 8);
            bf16x8 blo = ldfrag(frX + (ks * 2 + 1) * 512 + l * 8);
            #pragma unroll
            for (int mt = 0; mt < 4; mt++) {
                const float xm = RS[mt * 16 + n16];
                f32x4 h0, h1v;
                #pragma unroll
                for (int i = 0; i < 4; i++) {
                    h0[i]  = fmaxf(fmaf(xm, w1a[i], b1a[i]), 0.0f);
                    h1v[i] = fmaxf(fmaf(xm, w1b[i], b1b[i]), 0.0f);
                }
                bf16x8 ahi, alo; split8(h0, h1v, ahi, alo);
                accX[mt] = MFMA(ahi, bhi, accX[mt]);
                accX[mt] = MFMA(alo, bhi, accX[mt]);
                accX[mt] = MFMA(ahi, blo, accX[mt]);
            }
        }
        const float tev = teo[(b * 12 + p) * 64 + col];
        __syncthreads();   // all x reads from RS done before XE write (XE distinct, but
                           // RS gets overwritten inside gru_layer rs-phase of layer 1)
        #pragma unroll
        for (int mt = 0; mt < 4; mt++)
            #pragma unroll
            for (int r = 0; r < 4; r++) {
                int tok = mt * 16 + q * 4 + r;
                XE[SW(tok, col)] = accX[mt][r] + se[mt][r] + tev;
            }
        __syncthreads();   // XE complete

        gru_layer(XE, S1, RS, frG1, frC1, bg1, bc1, l, w);
        gru_layer(S1, S2, RS, frG2, frC2, bg2, bc2, l, w);
    }

    // ---- head: h = relu(S2@Wo1+bo1) via MFMA (into XE), then tiny y GEMV ----
    f32x4 accH[4];
    #pragma unroll
    for (int mt = 0; mt < 4; mt++) accH[mt] = (f32x4)0.0f;
    #pragma unroll
    for (int ks = 0; ks < 2; ks++) {
        bf16x8 bhi = ldfrag(frH + (ks * 2 + 0) * 512 + l * 8);
        bf16x8 blo = ldfrag(frH + (ks * 2 + 1) * 512 + l * 8);
        const int kk = ks * 32 + q * 8;
        #pragma unroll
        for (int mt = 0; mt < 4; mt++) {
            bf16x8 ahi, alo;
            lda_split(S2, mt * 16 + n16, kk, ahi, alo);
            accH[mt] = MFMA(ahi, bhi, accH[mt]);
            accH[mt] = MFMA(alo, bhi, accH[mt]);
            accH[mt] = MFMA(ahi, blo, accH[mt]);
        }
    }
    const float bo = bo1[col];
    #pragma unroll
    for (int mt = 0; mt < 4; mt++)
        #pragma unroll
        for (int r = 0; r < 4; r++) {
            int tok = mt * 16 + q * 4 + r;
            XE[SW(tok, col)] = fmaxf(accH[mt][r] + bo, 0.0f);
        }
    __syncthreads();
    // y: lane = token, wave owns 3 of the 12 q-cols
    const int uw = __builtin_amdgcn_readfirstlane(w);
    float y0 = bo2[3 * uw], y1 = bo2[3 * uw + 1], y2 = bo2[3 * uw + 2];
    #pragma unroll 8
    for (int j = 0; j < 64; j++) {
        const float hj = XE[SW(l, j)];
        y0 = fmaf(hj, Wo2[j * 12 + 3 * uw + 0], y0);
        y1 = fmaf(hj, Wo2[j * 12 + 3 * uw + 1], y1);
        y2 = fmaf(hj, Wo2[j * 12 + 3 * uw + 2], y2);
    }
    out[(b * 12 + 3 * uw + 0) * NB + n0 + l] = y0;
    out[(b * 12 + 3 * uw + 1) * NB + n0 + l] = y1;
    out[(b * 12 + 3 * uw + 2) * NB + n0 + l] = y2;
}

extern "C" void kernel_launch(void* const* d_in, const int* in_sizes, int n_in,
                              void* d_out, int out_size, void* d_ws, size_t ws_size,
                              hipStream_t stream) {
    const float* X    = (const float*)d_in[0];
    // d_in[1]=ZC, d_in[2]=ZF unused by the reference
    const float* SE   = (const float*)d_in[3];
    const float* Wse1 = (const float*)d_in[4];
    const float* bse1 = (const float*)d_in[5];
    const float* Wse2 = (const float*)d_in[6];
    const float* bse2 = (const float*)d_in[7];
    const float* Wte1 = (const float*)d_in[8];
    const float* bte1 = (const float*)d_in[9];
    const float* Wte2 = (const float*)d_in[10];
    const float* bte2 = (const float*)d_in[11];
    const float* Win1 = (const float*)d_in[12];
    const float* bin1 = (const float*)d_in[13];
    const float* Win2 = (const float*)d_in[14];
    const float* bin2 = (const float*)d_in[15];
    const float* Wg1  = (const float*)d_in[16];
    const float* bg1  = (const float*)d_in[17];
    const float* Wc1  = (const float*)d_in[18];
    const float* bc1  = (const float*)d_in[19];
    const float* Wg2  = (const float*)d_in[20];
    const float* bg2  = (const float*)d_in[21];
    const float* Wc2  = (const float*)d_in[22];
    const float* bc2  = (const float*)d_in[23];
    const float* Wo1  = (const float*)d_in[24];
    const float* bo1  = (const float*)d_in[25];
    const float* Wo2  = (const float*)d_in[26];
    const float* bo2  = (const float*)d_in[27];
    const int*   TE   = (const int*)d_in[28];

    float* ws = (float*)d_ws;                  // 172032 floats = 688 KB
    unsigned short* fr = (unsigned short*)ws;
    float* seB = ws + 57344;
    float* teo = ws + 122880;
    float* out = (float*)d_out;

    prep_gates<<<16, 256, 0, stream>>>(Wg1, Wg2, fr);
    prep_cand<<<8, 256, 0, stream>>>(Wc1, Wc2, fr);
    prep_small<<<4, 256, 0, stream>>>(Win2, Wo1, fr);
    prep_se<<<1024, 64, 0, stream>>>(SE, Wse1, bse1, Wse2, bse2, bin2, seB);
    prep_te<<<768, 64, 0, stream>>>(TE, Wte1, bte1, Wte2, bte2, teo);
    gman_main<<<1024, 256, 0, stream>>>(X, ws, Win1, bin1, bg1, bc1, bg2, bc2,
                                        bo1, Wo2, bo2, out);
}